// Round 1
// baseline (50.557 us; speedup 1.0000x reference)
//
#include <hip/hip_runtime.h>

// Problem constants
#define L_CNT 128
#define R_CNT 1024
#define T_CNT 16
#define E_CNT 32
#define F_CNT 64

// rbf = exp(-((d-mu)/sigma)^2), sigma = -0.3125 -> 1/sigma^2 = 10.24
// exp(-x) = exp2(-x*log2e). SFAC = sqrt(10.24*log2(e)) so that
// rbf = exp2(-((d - mu)*SFAC_over_sigma...)^2) == exp2(-(d*SFAC - mu*SFAC)^2)
constexpr float SFAC = 3.8435917f;               // sqrt(10.24 * 1.4426950408889634)
constexpr float MUS  = SFAC * (10.0f / 31.0f);   // mu step * SFAC

// ---------------------------------------------------------------------------
// Kernel A: atn[e][l][r] = sum_f lig[l,e,f] * rec[r,e,f]
// Grid: (32 e, 2 l-tiles, 8 r-tiles). Block 256 threads.
// Tile: 64 l x 128 r, K = 64. Thread tile: 4 l x 8 r (r interleaved by 16).
// ---------------------------------------------------------------------------
__global__ __launch_bounds__(256) void atn_kernel(const float* __restrict__ lig,
                                                  const float* __restrict__ rec,
                                                  float* __restrict__ atn) {
    const int e  = blockIdx.x;
    const int lt = blockIdx.y;
    const int rt = blockIdx.z;
    const int tid = threadIdx.x;

    // stride 68: 68*4B = 272B = 17*16 -> float4 aligned; bank spread OK
    __shared__ __align__(16) float As[64][68];
    __shared__ __align__(16) float Bs[128][68];

    const int l0 = lt * 64;
    const int r0 = rt * 128;

    // Stage A tile: 64 rows x 64 floats (coalesced: 16 lanes per row)
#pragma unroll
    for (int i = 0; i < 4; ++i) {
        int idx = i * 256 + tid;          // 1024 float4
        int l  = idx >> 4;
        int f4 = idx & 15;
        float4 v = *(const float4*)(lig + ((size_t)(l0 + l) * 32 + e) * 64 + f4 * 4);
        *(float4*)(&As[l][f4 * 4]) = v;
    }
    // Stage B tile: 128 rows x 64 floats
#pragma unroll
    for (int i = 0; i < 8; ++i) {
        int idx = i * 256 + tid;          // 2048 float4
        int r  = idx >> 4;
        int f4 = idx & 15;
        float4 v = *(const float4*)(rec + ((size_t)(r0 + r) * 32 + e) * 64 + f4 * 4);
        *(float4*)(&Bs[r][f4 * 4]) = v;
    }
    __syncthreads();

    const int tl = tid >> 4;   // 0..15 -> l block of 4
    const int tr = tid & 15;   // 0..15 -> r = tr + 16*m

    float acc[4][8];
#pragma unroll
    for (int j = 0; j < 4; ++j)
#pragma unroll
        for (int m = 0; m < 8; ++m) acc[j][m] = 0.0f;

    for (int k4 = 0; k4 < 16; ++k4) {
        float4 a[4];
        float4 b[8];
#pragma unroll
        for (int j = 0; j < 4; ++j) a[j] = *(float4*)(&As[tl * 4 + j][k4 * 4]);
#pragma unroll
        for (int m = 0; m < 8; ++m) b[m] = *(float4*)(&Bs[tr + 16 * m][k4 * 4]);
#pragma unroll
        for (int j = 0; j < 4; ++j)
#pragma unroll
            for (int m = 0; m < 8; ++m) {
                acc[j][m] = fmaf(a[j].x, b[m].x, acc[j][m]);
                acc[j][m] = fmaf(a[j].y, b[m].y, acc[j][m]);
                acc[j][m] = fmaf(a[j].z, b[m].z, acc[j][m]);
                acc[j][m] = fmaf(a[j].w, b[m].w, acc[j][m]);
            }
    }

    // Write atn[e][l][r]
#pragma unroll
    for (int j = 0; j < 4; ++j) {
        const size_t row = ((size_t)e * 128 + (l0 + tl * 4 + j)) * 1024 + r0;
#pragma unroll
        for (int m = 0; m < 8; ++m) {
            atn[row + tr + 16 * m] = acc[j][m];
        }
    }
}

// ---------------------------------------------------------------------------
// Kernel B: per (l,r) pair, accumulate acc[t] += atn[e,l,r]*exp2(-(d*SFAC-mu*SFAC)^2)
// Grid: 512 blocks (128 l x 4 r-chunks of 256). Block 256 threads, 1 pair/thread.
// ---------------------------------------------------------------------------
__global__ __launch_bounds__(256) void energy_kernel(const float* __restrict__ atn,
                                                     const float* __restrict__ ligc,
                                                     const float* __restrict__ recc,
                                                     float* __restrict__ partials) {
    const int tid = threadIdx.x;
    const int l = blockIdx.x >> 2;
    const int r = (blockIdx.x & 3) * 256 + tid;

    const float rx = recc[r * 3 + 0];
    const float ry = recc[r * 3 + 1];
    const float rz = recc[r * 3 + 2];

    float d[T_CNT];
#pragma unroll
    for (int t = 0; t < T_CNT; ++t) {
        float dx = ligc[((size_t)t * 128 + l) * 3 + 0] - rx;
        float dy = ligc[((size_t)t * 128 + l) * 3 + 1] - ry;
        float dz = ligc[((size_t)t * 128 + l) * 3 + 2] - rz;
        d[t] = sqrtf(dx * dx + dy * dy + dz * dz);
    }

    float acc[T_CNT];
#pragma unroll
    for (int t = 0; t < T_CNT; ++t) acc[t] = 0.0f;

    for (int e = 0; e < E_CNT; ++e) {
        const float ae  = atn[((size_t)e * 128 + l) * 1024 + r];
        const float mus = (float)e * MUS;
#pragma unroll
        for (int t = 0; t < T_CNT; ++t) {
            float u = fmaf(d[t], SFAC, -mus);
            acc[t] = fmaf(ae, exp2f(-(u * u)), acc[t]);
        }
    }

    // Block reduction: shuffle within wave, then LDS across 4 waves.
    __shared__ float red[4][T_CNT];
    const int lane = tid & 63;
    const int wid  = tid >> 6;
#pragma unroll
    for (int t = 0; t < T_CNT; ++t) {
#pragma unroll
        for (int m = 32; m >= 1; m >>= 1) acc[t] += __shfl_xor(acc[t], m, 64);
    }
    if (lane == 0) {
#pragma unroll
        for (int t = 0; t < T_CNT; ++t) red[wid][t] = acc[t];
    }
    __syncthreads();
    if (tid < T_CNT) {
        float s = red[0][tid] + red[1][tid] + red[2][tid] + red[3][tid];
        partials[(size_t)blockIdx.x * T_CNT + tid] = s;
    }
}

// ---------------------------------------------------------------------------
// Kernel C: deterministic final reduce of 512 x 16 partials -> out[16]
// ---------------------------------------------------------------------------
__global__ __launch_bounds__(256) void final_reduce(const float* __restrict__ partials,
                                                    float* __restrict__ out) {
    __shared__ float red[16][17];
    const int t = threadIdx.x & 15;
    const int g = threadIdx.x >> 4;   // 16 groups
    float s = 0.0f;
    for (int b = g; b < 512; b += 16) s += partials[(size_t)b * 16 + t];
    red[g][t] = s;
    __syncthreads();
    if (threadIdx.x < 16) {
        float v = 0.0f;
#pragma unroll
        for (int g2 = 0; g2 < 16; ++g2) v += red[g2][threadIdx.x];
        out[threadIdx.x] = v;
    }
}

extern "C" void kernel_launch(void* const* d_in, const int* in_sizes, int n_in,
                              void* d_out, int out_size, void* d_ws, size_t ws_size,
                              hipStream_t stream) {
    const float* lig  = (const float*)d_in[0];   // [128,32,64]
    const float* rec  = (const float*)d_in[1];   // [1024,32,64]
    const float* ligc = (const float*)d_in[2];   // [16,128,3]
    const float* recc = (const float*)d_in[3];   // [1024,3]
    float* out = (float*)d_out;                  // [16]

    float* atn      = (float*)d_ws;                          // 32*128*1024 floats = 16 MB
    float* partials = atn + (size_t)E_CNT * L_CNT * R_CNT;   // 512*16 floats

    atn_kernel<<<dim3(E_CNT, 2, 8), 256, 0, stream>>>(lig, rec, atn);
    energy_kernel<<<512, 256, 0, stream>>>(atn, ligc, recc, partials);
    final_reduce<<<1, 256, 0, stream>>>(partials, out);
}

// Round 2
// 37.953 us; speedup vs baseline: 1.3321x; 1.3321x over previous
//
#include <hip/hip_runtime.h>
#include <hip/hip_bf16.h>

// Problem constants
#define L_CNT 128
#define R_CNT 1024
#define T_CNT 16
#define E_CNT 32
#define F_CNT 64

// rbf = exp(-((d-mu)/sigma)^2), sigma = -0.3125 -> 1/sigma^2 = 10.24
// exp(-x) = exp2(-x*log2e). SFAC = sqrt(10.24*log2(e)).
constexpr float SFAC = 3.8435917f;               // sqrt(10.24 * 1.4426950408889634)
constexpr float MUS  = SFAC * (10.0f / 31.0f);   // mu step * SFAC

#if defined(__has_builtin)
#  if __has_builtin(__builtin_amdgcn_exp2f)
#    define EXP2(x) __builtin_amdgcn_exp2f(x)
#  endif
#endif
#ifndef EXP2
#  define EXP2(x) exp2f(x)
#endif

typedef __attribute__((ext_vector_type(8))) short short8_t;
typedef __attribute__((ext_vector_type(4))) float f32x4;

__device__ __forceinline__ short f2bf(float f) {
    unsigned u = __float_as_uint(f);
    u += 0x7fffu + ((u >> 16) & 1u);   // RNE
    return (short)(u >> 16);
}

// ---------------------------------------------------------------------------
// Kernel A: atn[e][l][r] (bf16) = sum_f lig[l,e,f] * rec[r,e,f], via bf16 MFMA.
// Grid (32 e, 2 lt, 8 rt), block 256 = 4 waves. Tile 64l x 128r, K=64.
// Wave w computes rows 16w..16w+15 x all 128 cols = 8 tiles of 16x16.
// LDS: bf16 tiles, row stride 72 shorts (144 B) -> balanced banks for b128.
// ---------------------------------------------------------------------------
#define PADK 72
__global__ __launch_bounds__(256) void atn_mfma(const float* __restrict__ lig,
                                                const float* __restrict__ rec,
                                                unsigned short* __restrict__ atn) {
    const int e   = blockIdx.x;
    const int l0  = blockIdx.y * 64;
    const int r0  = blockIdx.z * 128;
    const int tid = threadIdx.x;

    __shared__ __align__(16) short As[64 * PADK];
    __shared__ __align__(16) short Bs[128 * PADK];

    // Stage lig tile: 64 rows x 64 f -> 1024 float4, 4 per thread (cvt to bf16)
#pragma unroll
    for (int i = 0; i < 4; ++i) {
        int idx = i * 256 + tid;
        int row = idx >> 4;
        int f4  = idx & 15;
        float4 v = *(const float4*)(lig + ((size_t)(l0 + row) * 32 + e) * 64 + f4 * 4);
        short4 p;
        p.x = f2bf(v.x); p.y = f2bf(v.y); p.z = f2bf(v.z); p.w = f2bf(v.w);
        *(short4*)(&As[row * PADK + f4 * 4]) = p;
    }
    // Stage rec tile: 128 rows x 64 f -> 2048 float4, 8 per thread
#pragma unroll
    for (int i = 0; i < 8; ++i) {
        int idx = i * 256 + tid;
        int row = idx >> 4;
        int f4  = idx & 15;
        float4 v = *(const float4*)(rec + ((size_t)(r0 + row) * 32 + e) * 64 + f4 * 4);
        short4 p;
        p.x = f2bf(v.x); p.y = f2bf(v.y); p.z = f2bf(v.z); p.w = f2bf(v.w);
        *(short4*)(&Bs[row * PADK + f4 * 4]) = p;
    }
    __syncthreads();

    const int wave = tid >> 6;
    const int lane = tid & 63;
    const int fr   = lane & 15;        // A row within tile / B col within tile
    const int kg   = lane >> 4;        // k-group of 8

    f32x4 acc[8];
#pragma unroll
    for (int n = 0; n < 8; ++n) acc[n] = (f32x4){0.f, 0.f, 0.f, 0.f};

    // A fragments (this wave's 16 rows), kc = 0 / 1 (K=32 each)
    short8_t a0 = *(short8_t*)(&As[(16 * wave + fr) * PADK + kg * 8]);
    short8_t a1 = *(short8_t*)(&As[(16 * wave + fr) * PADK + 32 + kg * 8]);

#pragma unroll
    for (int n = 0; n < 8; ++n) {
        short8_t b0 = *(short8_t*)(&Bs[(16 * n + fr) * PADK + kg * 8]);
        short8_t b1 = *(short8_t*)(&Bs[(16 * n + fr) * PADK + 32 + kg * 8]);
        acc[n] = __builtin_amdgcn_mfma_f32_16x16x32_bf16(a0, b0, acc[n], 0, 0, 0);
        acc[n] = __builtin_amdgcn_mfma_f32_16x16x32_bf16(a1, b1, acc[n], 0, 0, 0);
    }

    // C/D layout (16x16x32): col = lane&15, row = (lane>>4)*4 + reg
    const int orow = l0 + 16 * wave + (lane >> 4) * 4;
    const int ocol = r0 + fr;
#pragma unroll
    for (int n = 0; n < 8; ++n) {
#pragma unroll
        for (int j = 0; j < 4; ++j) {
            size_t off = ((size_t)e * 128 + orow + j) * 1024 + ocol + 16 * n;
            atn[off] = (unsigned short)f2bf(acc[n][j]);
        }
    }
}

// ---------------------------------------------------------------------------
// Kernel B: per (l,r) pair, acc[t] += atn[e,l,r]*exp2(-(d*SFAC-mu*SFAC)^2)
// Grid 512 (128 l x 4 r-chunks), block 256, 1 pair/thread.
// Wave-uniform skip of (e,t) pairs where all lanes have exp2 arg < 2^-20.
// ---------------------------------------------------------------------------
__global__ __launch_bounds__(256) void energy_kernel(const unsigned short* __restrict__ atn,
                                                     const float* __restrict__ ligc,
                                                     const float* __restrict__ recc,
                                                     float* __restrict__ partials) {
    const int tid = threadIdx.x;
    const int l = blockIdx.x >> 2;
    const int r = (blockIdx.x & 3) * 256 + tid;

    const float rx = recc[r * 3 + 0];
    const float ry = recc[r * 3 + 1];
    const float rz = recc[r * 3 + 2];

    float d[T_CNT];
#pragma unroll
    for (int t = 0; t < T_CNT; ++t) {
        float dx = ligc[((size_t)t * 128 + l) * 3 + 0] - rx;
        float dy = ligc[((size_t)t * 128 + l) * 3 + 1] - ry;
        float dz = ligc[((size_t)t * 128 + l) * 3 + 2] - rz;
        d[t] = sqrtf(dx * dx + dy * dy + dz * dz);
    }

    float acc[T_CNT];
#pragma unroll
    for (int t = 0; t < T_CNT; ++t) acc[t] = 0.0f;

    for (int e = 0; e < E_CNT; ++e) {
        const unsigned short u16 = atn[((size_t)e * 128 + l) * 1024 + r];
        const float ae  = __uint_as_float((unsigned)u16 << 16);
        const float mus = (float)e * MUS;
#pragma unroll
        for (int t = 0; t < T_CNT; ++t) {
            float u = fmaf(d[t], SFAC, -mus);
            float q = u * u;
            if (__any(q < 20.0f)) {            // exp2(-20) ~ 1e-6: negligible if all lanes beyond
                acc[t] = fmaf(ae, EXP2(-q), acc[t]);
            }
        }
    }

    // Block reduction: shuffle within wave, then LDS across 4 waves.
    __shared__ float red[4][T_CNT];
    const int lane = tid & 63;
    const int wid  = tid >> 6;
#pragma unroll
    for (int t = 0; t < T_CNT; ++t) {
#pragma unroll
        for (int m = 32; m >= 1; m >>= 1) acc[t] += __shfl_xor(acc[t], m, 64);
    }
    if (lane == 0) {
#pragma unroll
        for (int t = 0; t < T_CNT; ++t) red[wid][t] = acc[t];
    }
    __syncthreads();
    if (tid < T_CNT) {
        float s = red[0][tid] + red[1][tid] + red[2][tid] + red[3][tid];
        partials[(size_t)blockIdx.x * T_CNT + tid] = s;
    }
}

// ---------------------------------------------------------------------------
// Kernel C: deterministic final reduce of 512 x 16 partials -> out[16]
// ---------------------------------------------------------------------------
__global__ __launch_bounds__(256) void final_reduce(const float* __restrict__ partials,
                                                    float* __restrict__ out) {
    __shared__ float red[16][17];
    const int t = threadIdx.x & 15;
    const int g = threadIdx.x >> 4;
    float s = 0.0f;
    for (int b = g; b < 512; b += 16) s += partials[(size_t)b * 16 + t];
    red[g][t] = s;
    __syncthreads();
    if (threadIdx.x < 16) {
        float v = 0.0f;
#pragma unroll
        for (int g2 = 0; g2 < 16; ++g2) v += red[g2][threadIdx.x];
        out[threadIdx.x] = v;
    }
}

extern "C" void kernel_launch(void* const* d_in, const int* in_sizes, int n_in,
                              void* d_out, int out_size, void* d_ws, size_t ws_size,
                              hipStream_t stream) {
    const float* lig  = (const float*)d_in[0];   // [128,32,64]
    const float* rec  = (const float*)d_in[1];   // [1024,32,64]
    const float* ligc = (const float*)d_in[2];   // [16,128,3]
    const float* recc = (const float*)d_in[3];   // [1024,3]
    float* out = (float*)d_out;                  // [16]

    unsigned short* atn = (unsigned short*)d_ws;                       // 8 MB bf16
    float* partials = (float*)((char*)d_ws + (size_t)E_CNT * L_CNT * R_CNT * 2);

    atn_mfma<<<dim3(E_CNT, 2, 8), 256, 0, stream>>>(lig, rec, atn);
    energy_kernel<<<512, 256, 0, stream>>>(atn, ligc, recc, partials);
    final_reduce<<<1, 256, 0, stream>>>(partials, out);
}

// Round 3
// 28.081 us; speedup vs baseline: 1.8004x; 1.3515x over previous
//
#include <hip/hip_runtime.h>
#include <hip/hip_bf16.h>

// Problem constants
#define L_CNT 128
#define R_CNT 1024
#define T_CNT 16
#define E_CNT 32
#define F_CNT 64

// rbf = exp(-((d-mu)/sigma)^2), sigma = -0.3125 -> 1/sigma^2 = 10.24
// exp(-x) = exp2(-x*log2e). SFAC = sqrt(10.24*log2(e)).
// In exp2 domain: rbf_e(d) = exp2(-(d*SFAC - e*MUS)^2), MUS = SFAC*10/31.
constexpr float SFAC    = 3.8435917f;              // sqrt(10.24 * 1.4426950408889634)
constexpr float MUS     = SFAC * (10.0f / 31.0f);  // 1.2398683
constexpr float INV_MUS = 1.0f / MUS;

#if defined(__has_builtin)
#  if __has_builtin(__builtin_amdgcn_exp2f)
#    define EXP2(x) __builtin_amdgcn_exp2f(x)
#  endif
#endif
#ifndef EXP2
#  define EXP2(x) exp2f(x)
#endif

typedef __attribute__((ext_vector_type(8))) short short8_t;
typedef __attribute__((ext_vector_type(4))) float f32x4;

// fp32 -> bf16 RNE. __bf16 cast lowers to v_cvt_pk_bf16_f32 (pairs) on gfx950.
__device__ __forceinline__ short f2bf(float f) {
    __bf16 h = (__bf16)f;
    return __builtin_bit_cast(short, h);
}

// ---------------------------------------------------------------------------
// Kernel A: atn[e][l][r] (bf16) = sum_f lig[l,e,f] * rec[r,e,f], via bf16 MFMA.
// Grid (32 e, 2 lt, 8 rt), block 256 = 4 waves. Tile 64l x 128r, K=64.
// Wave w computes rows 16w..16w+15 x all 128 cols = 8 tiles of 16x16.
// LDS: bf16 tiles, row stride 72 shorts (144 B).
// ---------------------------------------------------------------------------
#define PADK 72
__global__ __launch_bounds__(256) void atn_mfma(const float* __restrict__ lig,
                                                const float* __restrict__ rec,
                                                unsigned short* __restrict__ atn) {
    const int e   = blockIdx.x;
    const int l0  = blockIdx.y * 64;
    const int r0  = blockIdx.z * 128;
    const int tid = threadIdx.x;

    __shared__ __align__(16) short As[64 * PADK];
    __shared__ __align__(16) short Bs[128 * PADK];

    // Stage lig tile: 64 rows x 64 f -> 1024 float4, 4 per thread (cvt to bf16)
#pragma unroll
    for (int i = 0; i < 4; ++i) {
        int idx = i * 256 + tid;
        int row = idx >> 4;
        int f4  = idx & 15;
        float4 v = *(const float4*)(lig + ((size_t)(l0 + row) * 32 + e) * 64 + f4 * 4);
        short4 p;
        p.x = f2bf(v.x); p.y = f2bf(v.y); p.z = f2bf(v.z); p.w = f2bf(v.w);
        *(short4*)(&As[row * PADK + f4 * 4]) = p;
    }
    // Stage rec tile: 128 rows x 64 f -> 2048 float4, 8 per thread
#pragma unroll
    for (int i = 0; i < 8; ++i) {
        int idx = i * 256 + tid;
        int row = idx >> 4;
        int f4  = idx & 15;
        float4 v = *(const float4*)(rec + ((size_t)(r0 + row) * 32 + e) * 64 + f4 * 4);
        short4 p;
        p.x = f2bf(v.x); p.y = f2bf(v.y); p.z = f2bf(v.z); p.w = f2bf(v.w);
        *(short4*)(&Bs[row * PADK + f4 * 4]) = p;
    }
    __syncthreads();

    const int wave = tid >> 6;
    const int lane = tid & 63;
    const int fr   = lane & 15;        // A row within tile / B col within tile
    const int kg   = lane >> 4;        // k-group of 8

    f32x4 acc[8];
#pragma unroll
    for (int n = 0; n < 8; ++n) acc[n] = (f32x4){0.f, 0.f, 0.f, 0.f};

    short8_t a0 = *(short8_t*)(&As[(16 * wave + fr) * PADK + kg * 8]);
    short8_t a1 = *(short8_t*)(&As[(16 * wave + fr) * PADK + 32 + kg * 8]);

#pragma unroll
    for (int n = 0; n < 8; ++n) {
        short8_t b0 = *(short8_t*)(&Bs[(16 * n + fr) * PADK + kg * 8]);
        short8_t b1 = *(short8_t*)(&Bs[(16 * n + fr) * PADK + 32 + kg * 8]);
        acc[n] = __builtin_amdgcn_mfma_f32_16x16x32_bf16(a0, b0, acc[n], 0, 0, 0);
        acc[n] = __builtin_amdgcn_mfma_f32_16x16x32_bf16(a1, b1, acc[n], 0, 0, 0);
    }

    // C/D layout (16x16x32): col = lane&15, row = (lane>>4)*4 + reg
    const int orow = l0 + 16 * wave + (lane >> 4) * 4;
    const int ocol = r0 + fr;
#pragma unroll
    for (int n = 0; n < 8; ++n) {
#pragma unroll
        for (int j = 0; j < 4; ++j) {
            size_t off = ((size_t)e * 128 + orow + j) * 1024 + ocol + 16 * n;
            atn[off] = (unsigned short)f2bf(acc[n][j]);
        }
    }
}

// ---------------------------------------------------------------------------
// Kernel B: per (l,r) pair, acc[t] += atn[e,l,r]*exp2(-(d*SFAC - e*MUS)^2)
// summed only over the 7-wide e-window around e0 = round(d*SFAC/MUS):
// terms outside |e-e0|>3 have rbf < 2.2e-6 (signed-random sum error ~0.02).
// Grid 512 (128 l x 4 r-chunks of 256), block 256, 1 pair/thread.
// atn for the block's 256 pairs staged in LDS [e][r] for per-thread e-gather
// (register arrays can't be runtime-indexed without spilling to scratch).
// ---------------------------------------------------------------------------
__global__ __launch_bounds__(256) void energy_kernel(const unsigned short* __restrict__ atn,
                                                     const float* __restrict__ ligc,
                                                     const float* __restrict__ recc,
                                                     float* __restrict__ partials) {
    __shared__ unsigned int atn_sd[E_CNT * 128];          // [32][256] bf16 = 16 KB
    const unsigned short* atn_su = (const unsigned short*)atn_sd;

    const int tid   = threadIdx.x;
    const int l     = blockIdx.x >> 2;
    const int rbase = (blockIdx.x & 3) * 256;
    const int r     = rbase + tid;

    // --- T14 split: issue atn dword loads early (32 e x 256 r = 4096 dwords) ---
    const unsigned int* atn_d = (const unsigned int*)atn;   // 2 bf16 per dword
    unsigned int stage[16];
#pragma unroll
    for (int it = 0; it < 16; ++it) {
        int idx = it * 256 + tid;          // dword slot in LDS
        int e   = idx >> 7;                // 128 dwords per e-row
        int rh  = idx & 127;
        stage[it] = atn_d[(size_t)e * 65536 + (size_t)l * 512 + (rbase >> 1) + rh];
    }

    // --- distances (overlaps the loads above) ---
    const float rx = recc[r * 3 + 0];
    const float ry = recc[r * 3 + 1];
    const float rz = recc[r * 3 + 2];

    float d[T_CNT];
#pragma unroll
    for (int t = 0; t < T_CNT; ++t) {
        float dx = ligc[((size_t)t * 128 + l) * 3 + 0] - rx;
        float dy = ligc[((size_t)t * 128 + l) * 3 + 1] - ry;
        float dz = ligc[((size_t)t * 128 + l) * 3 + 2] - rz;
        d[t] = sqrtf(dx * dx + dy * dy + dz * dz);
    }

    // --- write staged atn to LDS ---
#pragma unroll
    for (int it = 0; it < 16; ++it) atn_sd[it * 256 + tid] = stage[it];
    __syncthreads();

    float acc[T_CNT];
#pragma unroll
    for (int t = 0; t < T_CNT; ++t) acc[t] = 0.0f;

#pragma unroll
    for (int t = 0; t < T_CNT; ++t) {
        const float u   = d[t] * SFAC;
        float e0f = rintf(u * INV_MUS);
        e0f = fminf(fmaxf(e0f, 3.0f), 28.0f);   // window [e0-3, e0+3] stays in [0,31]
        const int   em3 = (int)e0f - 3;
        const float um  = fmaf(e0f, -MUS, u);   // u - e0*MUS, |um| <= MUS/2 away from clamp
#pragma unroll
        for (int k = 0; k < 7; ++k) {
            const float w  = um - (float)(k - 3) * MUS;
            const float ae = __uint_as_float((unsigned)atn_su[(em3 + k) * 256 + tid] << 16);
            acc[t] = fmaf(ae, EXP2(-(w * w)), acc[t]);
        }
    }

    // Block reduction: shuffle within wave, then LDS across 4 waves.
    __shared__ float red[4][T_CNT];
    const int lane = tid & 63;
    const int wid  = tid >> 6;
#pragma unroll
    for (int t = 0; t < T_CNT; ++t) {
#pragma unroll
        for (int m = 32; m >= 1; m >>= 1) acc[t] += __shfl_xor(acc[t], m, 64);
    }
    if (lane == 0) {
#pragma unroll
        for (int t = 0; t < T_CNT; ++t) red[wid][t] = acc[t];
    }
    __syncthreads();
    if (tid < T_CNT) {
        float s = red[0][tid] + red[1][tid] + red[2][tid] + red[3][tid];
        partials[(size_t)blockIdx.x * T_CNT + tid] = s;
    }
}

// ---------------------------------------------------------------------------
// Kernel C: deterministic final reduce of 512 x 16 partials -> out[16]
// ---------------------------------------------------------------------------
__global__ __launch_bounds__(256) void final_reduce(const float* __restrict__ partials,
                                                    float* __restrict__ out) {
    __shared__ float red[16][17];
    const int t = threadIdx.x & 15;
    const int g = threadIdx.x >> 4;
    float s = 0.0f;
    for (int b = g; b < 512; b += 16) s += partials[(size_t)b * 16 + t];
    red[g][t] = s;
    __syncthreads();
    if (threadIdx.x < 16) {
        float v = 0.0f;
#pragma unroll
        for (int g2 = 0; g2 < 16; ++g2) v += red[g2][threadIdx.x];
        out[threadIdx.x] = v;
    }
}

extern "C" void kernel_launch(void* const* d_in, const int* in_sizes, int n_in,
                              void* d_out, int out_size, void* d_ws, size_t ws_size,
                              hipStream_t stream) {
    const float* lig  = (const float*)d_in[0];   // [128,32,64]
    const float* rec  = (const float*)d_in[1];   // [1024,32,64]
    const float* ligc = (const float*)d_in[2];   // [16,128,3]
    const float* recc = (const float*)d_in[3];   // [1024,3]
    float* out = (float*)d_out;                  // [16]

    unsigned short* atn = (unsigned short*)d_ws;                       // 8 MB bf16
    float* partials = (float*)((char*)d_ws + (size_t)E_CNT * L_CNT * R_CNT * 2);

    atn_mfma<<<dim3(E_CNT, 2, 8), 256, 0, stream>>>(lig, rec, atn);
    energy_kernel<<<512, 256, 0, stream>>>(atn, ligc, recc, partials);
    final_reduce<<<1, 256, 0, stream>>>(partials, out);
}